// Round 6
// baseline (245.741 us; speedup 1.0000x reference)
//
#include <hip/hip_runtime.h>

#define N_TOK  8192
#define KDIM   4096
#define NE     16
#define NSLICE 8                   // ws partials per token (one per k-octant block)
#define TB     64                  // tokens per block (= wave width)

// R12: vector-path gate loads (the real bottleneck theory).
// Five x-side probes (TLP 8/16/32 waves, run length 256B/512B/1KB, burst
// depth, LDS vs direct) are ALL flat -> x-streaming is not the limiter.
// R6's signature (VALUBusy 8% AND only 775 GB/s) fits one thing: waves
// stalled on lgkmcnt for SCALAR gate loads. gb is provably wave-uniform ->
// compiler emits s_load via the scalar K$, which has ~2 outstanding misses
// and 256KB gate doesn't fit it -> inner loop serializes on ~200cy L2 hits.
// Scalar path is per-CU shared: explains R10 (more waves, flat) and R8
// (fewer waves, +13us) and R6~=R7 (same gate path, different x paths).
// Fix: launder 0 through a VGPR into the gate address so it is not provably
// uniform -> global_load_dwordx4 (TCP, deep miss queue, L1/L2-cached;
// uniform addr coalesces to one 64B request/instr). x path = R7 exactly.
// VGPR ~110 < 128 -> occupancy unchanged (4 waves/SIMD, 16 waves/CU).
// Prediction: partial ~80-100 -> ~25-30us, total 197 -> ~130-150, VALUBusy
// up several x. Flat => scalar path was fine => declare roofline next round.
__global__ __launch_bounds__(256, 4)
void router_partial(const float* __restrict__ x, const float* __restrict__ gate,
                    float* __restrict__ ws) {
  __shared__ float red[256 * 17];            // cross-wave reduction only
  const int tid  = threadIdx.x;
  const int lane = tid & 63;
  const int w    = __builtin_amdgcn_readfirstlane(tid >> 6);
  const int g    = blockIdx.x >> 3;          // token group (128)
  const int q    = blockIdx.x & 7;           // k-octant (8) -> ws slice
  const int t0   = g * TB;
  const int sid  = q * 4 + w;                // 32 strips of 128 k
  const int k0   = sid * 128;

  const float4* xr = (const float4*)(x + (size_t)(t0 + lane) * KDIM + k0);

  // Launder a zero through a VGPR: gate address no longer provably uniform,
  // so the compiler must use the vector memory path instead of s_load.
  int vzero;
  asm volatile("v_mov_b32 %0, 0" : "=v"(vzero));
  // gate row k = 4 float4 (16 experts). gB indexed in float4 units.
  const float4* gB = (const float4*)gate + (((size_t)k0) << 2) + vzero;

  float acc[NE];
#pragma unroll
  for (int e = 0; e < NE; ++e) acc[e] = 0.f;

  // x: 32 float4 loads per lane (512B strip), 2-deep ping-pong, one 64B line
  // per iteration in flight during each 256-FMA block (R7's best geometry).
  // All indices compile-time after unroll -> stays in VGPRs (rule-#20 safe).
  float4 cur[4], nxt[4];
#pragma unroll
  for (int u = 0; u < 4; ++u) cur[u] = xr[u];
#pragma unroll
  for (int jc = 0; jc < 8; ++jc) {
    if (jc < 7) {
#pragma unroll
      for (int u = 0; u < 4; ++u) nxt[u] = xr[(jc + 1) * 4 + u];
    }
#pragma unroll
    for (int u = 0; u < 4; ++u) {
      const float xv[4] = {cur[u].x, cur[u].y, cur[u].z, cur[u].w};
#pragma unroll
      for (int m = 0; m < 4; ++m) {
        const int row = jc * 16 + u * 4 + m;           // compile-time
        const float4 g0 = gB[(row << 2) + 0];          // vector loads,
        const float4 g1 = gB[(row << 2) + 1];          // uniform addr ->
        const float4 g2 = gB[(row << 2) + 2];          // 1x64B L2 req each
        const float4 g3 = gB[(row << 2) + 3];
        const float xm = xv[m];
        acc[0]  = fmaf(xm, g0.x, acc[0]);
        acc[1]  = fmaf(xm, g0.y, acc[1]);
        acc[2]  = fmaf(xm, g0.z, acc[2]);
        acc[3]  = fmaf(xm, g0.w, acc[3]);
        acc[4]  = fmaf(xm, g1.x, acc[4]);
        acc[5]  = fmaf(xm, g1.y, acc[5]);
        acc[6]  = fmaf(xm, g1.z, acc[6]);
        acc[7]  = fmaf(xm, g1.w, acc[7]);
        acc[8]  = fmaf(xm, g2.x, acc[8]);
        acc[9]  = fmaf(xm, g2.y, acc[9]);
        acc[10] = fmaf(xm, g2.z, acc[10]);
        acc[11] = fmaf(xm, g2.w, acc[11]);
        acc[12] = fmaf(xm, g3.x, acc[12]);
        acc[13] = fmaf(xm, g3.y, acc[13]);
        acc[14] = fmaf(xm, g3.z, acc[14]);
        acc[15] = fmaf(xm, g3.w, acc[15]);
      }
    }
#pragma unroll
    for (int u = 0; u < 4; ++u) cur[u] = nxt[u];
  }

  // cross-wave reduction (4 strips of 128k -> one 512k partial), then one
  // float4 per thread into ws[q]
  __syncthreads();
#pragma unroll
  for (int e = 0; e < NE; ++e) red[(w * 64 + lane) * 17 + e] = acc[e];
  __syncthreads();
  {
    int p0 = tid * 4;                        // 1024 (token,e) pairs, 4/thread
    int t  = p0 >> 4, e0 = p0 & 15;
    float v[4];
#pragma unroll
    for (int j = 0; j < 4; ++j) {
      float sum = 0.f;
#pragma unroll
      for (int ww = 0; ww < 4; ++ww) sum += red[(ww * 64 + t) * 17 + e0 + j];
      v[j] = sum;
    }
    *(float4*)(ws + ((size_t)q * N_TOK + (t0 + t)) * NE + e0) =
        make_float4(v[0], v[1], v[2], v[3]);
  }
}

// Sum 8 slice partials, top-2 (earliest-index tie-break = jax top_k),
// sigmoid, scatter into (E,N) scores; token_indices[e][t] = t (as float).
__global__ __launch_bounds__(256)
void router_finalize(const float* __restrict__ ws, float* __restrict__ out) {
  int t = blockIdx.x * 256 + threadIdx.x;
  float l[NE];
#pragma unroll
  for (int e = 0; e < NE; ++e) l[e] = 0.f;
#pragma unroll
  for (int s = 0; s < NSLICE; ++s) {
    const float4* row = (const float4*)(ws + ((size_t)s * N_TOK + t) * NE);
    float4 r0 = row[0], r1 = row[1], r2 = row[2], r3 = row[3];
    l[0]  += r0.x; l[1]  += r0.y; l[2]  += r0.z; l[3]  += r0.w;
    l[4]  += r1.x; l[5]  += r1.y; l[6]  += r1.z; l[7]  += r1.w;
    l[8]  += r2.x; l[9]  += r2.y; l[10] += r2.z; l[11] += r2.w;
    l[12] += r3.x; l[13] += r3.y; l[14] += r3.z; l[15] += r3.w;
  }
  int i1 = 0; float v1 = l[0];
#pragma unroll
  for (int e = 1; e < NE; ++e) { if (l[e] > v1) { v1 = l[e]; i1 = e; } }
  int i2 = -1; float v2 = -1e30f;
#pragma unroll
  for (int e = 0; e < NE; ++e) { if (e != i1 && l[e] > v2) { v2 = l[e]; i2 = e; } }
  float s1 = 1.f / (1.f + __expf(-v1));
  float s2 = 1.f / (1.f + __expf(-v2));
  float* scores = out;
  float* tix    = out + (size_t)NE * N_TOK;
  float tf = (float)t;
#pragma unroll
  for (int e = 0; e < NE; ++e) {             // coalesced across lanes per e
    scores[(size_t)e * N_TOK + t] = (e == i1) ? s1 : ((e == i2) ? s2 : 0.f);
    tix[(size_t)e * N_TOK + t]    = tf;
  }
}

extern "C" void kernel_launch(void* const* d_in, const int* in_sizes, int n_in,
                              void* d_out, int out_size, void* d_ws, size_t ws_size,
                              hipStream_t stream) {
  const float* x    = (const float*)d_in[0];
  const float* gate = (const float*)d_in[1];
  float* out = (float*)d_out;
  float* ws  = (float*)d_ws;   // needs NSLICE*N_TOK*NE*4 = 4 MB
  router_partial<<<dim3(N_TOK / TB * NSLICE), dim3(256), 0, stream>>>(x, gate, ws);
  router_finalize<<<dim3(N_TOK / 256), dim3(256), 0, stream>>>(ws, out);
}

// Round 7
// 201.704 us; speedup vs baseline: 1.2183x; 1.2183x over previous
//
#include <hip/hip_runtime.h>

#define N_TOK  8192
#define KDIM   4096
#define NE     16
#define NSLICE 8                   // ws partials per token (one per k-octant block)
#define TB     64                  // tokens per block (= wave width)

// R13: gate staged in LDS -- remove gate latency from the dependent chain.
// R12 finally exposed router_partial: 107us, VALUBusy 8.3%, 1.0 TB/s,
// VGPR=40. The +44us swing from changing ONLY the gate path (s_load ->
// per-use vector load; VGPR=40 proves the compiler collapsed the prefetch)
// proves the inner loop serializes on gate-load latency: 512 dependent
// ~300-500cy loads/wave. This retro-explains every flat x-side probe
// (R7/R8/R10/R11 shared the same gate chain) and R6's 8%-VALU/775GB/s
// signature. Fix: per-block gate strip (512 rows x 64B = 32KB) staged ONCE
// via coalesced float4 loads, inner loop reads it as ds_read_b128 at
// wave-uniform addresses (LDS broadcast, 0 conflicts, ~120cy, pipelined by
// compiler lgkmcnt across the fully-unrolled rows). x = R7's proven stream
// (2-deep ping-pong, 512B strips). No dependent global loads remain in the
// loop. LDS 32KB (reduction reuses it after barrier) -> 4 blocks/CU = 16
// waves/CU (measured TLP sweet spot).
// Prediction: partial 107 -> 25-35us, VALUBusy -> ~25-30%, total -> ~160-172.
// If partial >=55us: gate wasn't the cure -> attack per-lane x TA cost next.
__global__ __launch_bounds__(256, 4)
void router_partial(const float* __restrict__ x, const float* __restrict__ gate,
                    float* __restrict__ ws) {
  __shared__ __align__(16) float glds[512 * 16];   // 32KB gate strip; reused as red[]
  const int tid  = threadIdx.x;
  const int lane = tid & 63;
  const int w    = __builtin_amdgcn_readfirstlane(tid >> 6);
  const int g    = blockIdx.x >> 3;          // token group (128)
  const int q    = blockIdx.x & 7;           // k-octant (8) -> ws slice
  const int t0   = g * TB;
  const int sid  = q * 4 + w;                // 32 strips of 128 k
  const int k0   = sid * 128;

  // ---- stage gate rows [q*512, q*512+512) x 16 floats into LDS ----
  // 2048 float4 total; thread tid loads float4 u*256+tid (coalesced 4KB runs)
  {
    const float4* gsrc = (const float4*)(gate + (size_t)(q * 512) * NE);
    float4* gdst = (float4*)glds;
#pragma unroll
    for (int u = 0; u < 8; ++u) gdst[u * 256 + tid] = gsrc[u * 256 + tid];
  }
  __syncthreads();
  // wave w's rows are local rows [w*128, w*128+128)
  const float4* gl4 = (const float4*)glds;   // row r -> gl4[r*4 .. r*4+3]

  const float4* xr = (const float4*)(x + (size_t)(t0 + lane) * KDIM + k0);

  float acc[NE];
#pragma unroll
  for (int e = 0; e < NE; ++e) acc[e] = 0.f;

  // x: 32 float4 loads per lane (512B strip), 2-deep ping-pong, one 64B line
  // in flight during each 256-FMA block (R7's best-measured geometry).
  float4 cur[4], nxt[4];
#pragma unroll
  for (int u = 0; u < 4; ++u) cur[u] = xr[u];
#pragma unroll
  for (int jc = 0; jc < 8; ++jc) {
    if (jc < 7) {
#pragma unroll
      for (int u = 0; u < 4; ++u) nxt[u] = xr[(jc + 1) * 4 + u];
    }
#pragma unroll
    for (int u = 0; u < 4; ++u) {
      const float xv[4] = {cur[u].x, cur[u].y, cur[u].z, cur[u].w};
#pragma unroll
      for (int m = 0; m < 4; ++m) {
        const int r = w * 128 + jc * 16 + u * 4 + m;   // local gate row
        const float4 g0 = gl4[r * 4 + 0];  // ds_read_b128, uniform addr ->
        const float4 g1 = gl4[r * 4 + 1];  // broadcast, conflict-free
        const float4 g2 = gl4[r * 4 + 2];
        const float4 g3 = gl4[r * 4 + 3];
        const float xm = xv[m];
        acc[0]  = fmaf(xm, g0.x, acc[0]);
        acc[1]  = fmaf(xm, g0.y, acc[1]);
        acc[2]  = fmaf(xm, g0.z, acc[2]);
        acc[3]  = fmaf(xm, g0.w, acc[3]);
        acc[4]  = fmaf(xm, g1.x, acc[4]);
        acc[5]  = fmaf(xm, g1.y, acc[5]);
        acc[6]  = fmaf(xm, g1.z, acc[6]);
        acc[7]  = fmaf(xm, g1.w, acc[7]);
        acc[8]  = fmaf(xm, g2.x, acc[8]);
        acc[9]  = fmaf(xm, g2.y, acc[9]);
        acc[10] = fmaf(xm, g2.z, acc[10]);
        acc[11] = fmaf(xm, g2.w, acc[11]);
        acc[12] = fmaf(xm, g3.x, acc[12]);
        acc[13] = fmaf(xm, g3.y, acc[13]);
        acc[14] = fmaf(xm, g3.z, acc[14]);
        acc[15] = fmaf(xm, g3.w, acc[15]);
      }
    }
#pragma unroll
    for (int u = 0; u < 4; ++u) cur[u] = nxt[u];
  }

  // cross-wave reduction (4 strips of 128k -> one 512k partial), reusing
  // glds as red[256][17] (4352 floats < 8192). Barrier: all waves must be
  // done reading their gate rows before we overwrite.
  __syncthreads();
  float* red = glds;
#pragma unroll
  for (int e = 0; e < NE; ++e) red[(w * 64 + lane) * 17 + e] = acc[e];
  __syncthreads();
  {
    int p0 = tid * 4;                        // 1024 (token,e) pairs, 4/thread
    int t  = p0 >> 4, e0 = p0 & 15;
    float v[4];
#pragma unroll
    for (int j = 0; j < 4; ++j) {
      float sum = 0.f;
#pragma unroll
      for (int ww = 0; ww < 4; ++ww) sum += red[(ww * 64 + t) * 17 + e0 + j];
      v[j] = sum;
    }
    *(float4*)(ws + ((size_t)q * N_TOK + (t0 + t)) * NE + e0) =
        make_float4(v[0], v[1], v[2], v[3]);
  }
}

// Sum 8 slice partials, top-2 (earliest-index tie-break = jax top_k),
// sigmoid, scatter into (E,N) scores; token_indices[e][t] = t (as float).
__global__ __launch_bounds__(256)
void router_finalize(const float* __restrict__ ws, float* __restrict__ out) {
  int t = blockIdx.x * 256 + threadIdx.x;
  float l[NE];
#pragma unroll
  for (int e = 0; e < NE; ++e) l[e] = 0.f;
#pragma unroll
  for (int s = 0; s < NSLICE; ++s) {
    const float4* row = (const float4*)(ws + ((size_t)s * N_TOK + t) * NE);
    float4 r0 = row[0], r1 = row[1], r2 = row[2], r3 = row[3];
    l[0]  += r0.x; l[1]  += r0.y; l[2]  += r0.z; l[3]  += r0.w;
    l[4]  += r1.x; l[5]  += r1.y; l[6]  += r1.z; l[7]  += r1.w;
    l[8]  += r2.x; l[9]  += r2.y; l[10] += r2.z; l[11] += r2.w;
    l[12] += r3.x; l[13] += r3.y; l[14] += r3.z; l[15] += r3.w;
  }
  int i1 = 0; float v1 = l[0];
#pragma unroll
  for (int e = 1; e < NE; ++e) { if (l[e] > v1) { v1 = l[e]; i1 = e; } }
  int i2 = -1; float v2 = -1e30f;
#pragma unroll
  for (int e = 0; e < NE; ++e) { if (e != i1 && l[e] > v2) { v2 = l[e]; i2 = e; } }
  float s1 = 1.f / (1.f + __expf(-v1));
  float s2 = 1.f / (1.f + __expf(-v2));
  float* scores = out;
  float* tix    = out + (size_t)NE * N_TOK;
  float tf = (float)t;
#pragma unroll
  for (int e = 0; e < NE; ++e) {             // coalesced across lanes per e
    scores[(size_t)e * N_TOK + t] = (e == i1) ? s1 : ((e == i2) ? s2 : 0.f);
    tix[(size_t)e * N_TOK + t]    = tf;
  }
}

extern "C" void kernel_launch(void* const* d_in, const int* in_sizes, int n_in,
                              void* d_out, int out_size, void* d_ws, size_t ws_size,
                              hipStream_t stream) {
  const float* x    = (const float*)d_in[0];
  const float* gate = (const float*)d_in[1];
  float* out = (float*)d_out;
  float* ws  = (float*)d_ws;   // needs NSLICE*N_TOK*NE*4 = 4 MB
  router_partial<<<dim3(N_TOK / TB * NSLICE), dim3(256), 0, stream>>>(x, gate, ws);
  router_finalize<<<dim3(N_TOK / 256), dim3(256), 0, stream>>>(ws, out);
}